// Round 4
// baseline (129.118 us; speedup 1.0000x reference)
//
#include <hip/hip_runtime.h>

// MEASUREMENT ROUND: R3's passing kernel, launched 1x for real (-> out) plus
// 3x duplicates writing into d_ws (identical GPU work, dummy dest). The dur
// delta vs R3 (88.4us) gives 3x the kernel's true GPU time, resolving whether
// the ~42us non-fill budget is our kernel or fixed harness cost. If the kernel
// is slow, its replica rows are forced into rocprof's top-5, giving us its
// counters for the first time.
//
// out[b,n] = 1/(16*50625) * sum_j Acoeff[n,j] * S[b,j]
// S[b,j]   = sum_n Bbasis[j,n] * (M @ T[b,j])[n]
// T[b,j,m] = sum_{p,q,r,s} w[j1][p] w[j2][q] w[j3][r] w[j4][s] * arr[b,p,q,r,s,m]
// w masks: class0 0x36DB, class1 0x6DB6, class2 0xDB6C

static __device__ __forceinline__ void add4(float4& a, const float4& b) {
    a.x += b.x; a.y += b.y; a.z += b.z; a.w += b.w;
}
static __device__ __forceinline__ void fma4(float4& a, float w, const float4& b) {
    a.x = fmaf(w, b.x, a.x); a.y = fmaf(w, b.y, a.y);
    a.z = fmaf(w, b.z, a.z); a.w = fmaf(w, b.w, a.w);
}

__global__ __launch_bounds__(128) void sdd4_fused(
    const float* __restrict__ arr,      // [4,16,16,16,16,32]
    const float* __restrict__ Mmat,     // [32,32]
    const float* __restrict__ Bbasis,   // [81,32]
    const float* __restrict__ Acoeff,   // [32,81]
    float* __restrict__ out)            // [4,32], pre-zeroed (or ws dummy)
{
    __shared__ float4 U_lds[400];        // [r*25 + cls*8 + mv]  (pad 24->25)
    __shared__ float  V_lds[9 * 33];     // [jj*33 + m]
    __shared__ float  Y_lds[9 * 33];     // [jj*33 + n]
    __shared__ float  M_lds[32 * 33];    // [n*33 + m]
    __shared__ float  B_lds[81 * 33];    // [j*33 + n]
    __shared__ float  pv[36];            // per-combo dot results
    __shared__ int    jfv[36];           // per-combo flat j index

    const int t  = threadIdx.x;
    const int bx = blockIdx.x;           // 0..1023
    const int b  = bx >> 8;
    const int p  = (bx >> 4) & 15;
    const int q  = bx & 15;

    // ---- stage M (32x32) and Bbasis (81x32) into padded LDS ----
    const float4* M4 = reinterpret_cast<const float4*>(Mmat);
    for (int i = t; i < 256; i += 128) {
        float4 v = M4[i];
        float* dst = &M_lds[(i >> 3) * 33 + (i & 7) * 4];
        dst[0] = v.x; dst[1] = v.y; dst[2] = v.z; dst[3] = v.w;
    }
    const float4* B4 = reinterpret_cast<const float4*>(Bbasis);
    for (int i = t; i < 648; i += 128) {
        float4 v = B4[i];
        float* dst = &B_lds[(i >> 3) * 33 + (i & 7) * 4];
        dst[0] = v.x; dst[1] = v.y; dst[2] = v.z; dst[3] = v.w;
    }

    // ---- main global read: tile arr[b,p,q,:,:,:], reduce over s per class ----
    const int r  = t >> 3;               // 0..15
    const int mv = t & 7;                // float4 index within m
    const float4* A4 = reinterpret_cast<const float4*>(arr);
    const size_t tile = (size_t)((b * 16 + p) * 16 + q) * 2048;

    float4 u0 = make_float4(0.f, 0.f, 0.f, 0.f), u1 = u0, u2 = u0;
    #pragma unroll
    for (int s = 0; s < 16; ++s) {
        float4 x = A4[tile + (size_t)(r * 16 + s) * 8 + mv];
        if ((0x36DBu >> s) & 1) add4(u0, x);
        if ((0x6DB6u >> s) & 1) add4(u1, x);
        if ((0xDB6Cu >> s) & 1) add4(u2, x);
    }
    U_lds[r * 25 +      mv] = u0;
    U_lds[r * 25 +  8 + mv] = u1;
    U_lds[r * 25 + 16 + mv] = u2;
    __syncthreads();

    // ---- reduce over r per class: V[j3][j4][m] ----
    if (t < 72) {
        const int j3  = t / 24;
        const int rem = t % 24;
        const int j4  = rem >> 3;
        const int mv2 = rem & 7;
        const unsigned msk = (j3 == 0) ? 0x36DBu : (j3 == 1 ? 0x6DB6u : 0xDB6Cu);
        float4 acc = make_float4(0.f, 0.f, 0.f, 0.f);
        #pragma unroll
        for (int rr = 0; rr < 16; ++rr) {
            float w = (float)((msk >> rr) & 1u);
            fma4(acc, w, U_lds[rr * 25 + j4 * 8 + mv2]);
        }
        const int jj = j3 * 3 + j4;
        float* dv = &V_lds[jj * 33 + mv2 * 4];
        dv[0] = acc.x; dv[1] = acc.y; dv[2] = acc.z; dv[3] = acc.w;
    }
    __syncthreads();

    // ---- Y[jj][n] = sum_m M[n][m] * V[jj][m]   (9 matvecs of 32x32) ----
    for (int o = t; o < 288; o += 128) {
        const int jj = o >> 5;
        const int n  = o & 31;
        float acc = 0.f;
        #pragma unroll
        for (int m = 0; m < 32; ++m)
            acc = fmaf(M_lds[n * 33 + m], V_lds[jj * 33 + m], acc);
        Y_lds[jj * 33 + n] = acc;
    }
    __syncthreads();

    // ---- per-(j1,j2) combos for this (p,q): dot with Bbasis row ----
    int l1_0, l1_1 = 0, n1;
    if      (p == 0)  { l1_0 = 0; n1 = 1; }
    else if (p == 15) { l1_0 = 2; n1 = 1; }
    else              { l1_0 = (p - 1) % 3; l1_1 = p % 3; n1 = 2; }
    int l2_0, l2_1 = 0, n2;
    if      (q == 0)  { l2_0 = 0; n2 = 1; }
    else if (q == 15) { l2_0 = 2; n2 = 1; }
    else              { l2_0 = (q - 1) % 3; l2_1 = q % 3; n2 = 2; }

    const int ncomb = n1 * n2 * 9;
    if (t < ncomb) {
        const int jj  = t % 9;           // j3*3 + j4
        const int c12 = t / 9;
        const int i1idx = (n2 == 2) ? (c12 >> 1) : c12;
        const int i2idx = (n2 == 2) ? (c12 & 1)  : 0;
        const int i1 = i1idx ? l1_1 : l1_0;
        const int i2 = i2idx ? l2_1 : l2_0;
        const int jf = (i1 * 3 + i2) * 9 + jj;
        float acc = 0.f;
        #pragma unroll
        for (int n = 0; n < 32; ++n)
            acc = fmaf(Y_lds[jj * 33 + n], B_lds[jf * 33 + n], acc);
        pv[t]  = acc;
        jfv[t] = jf;
    }
    __syncthreads();

    // ---- fold through Acoeff locally, one atomicAdd vector per block ----
    if (t < 32) {
        float acc = 0.f;
        for (int c = 0; c < ncomb; ++c)
            acc = fmaf(Acoeff[t * 81 + jfv[c]], pv[c], acc);
        atomicAdd(&out[b * 32 + t], acc * (1.0f / 810000.0f)); // 1/(16*15^4)
    }
}

extern "C" void kernel_launch(void* const* d_in, const int* in_sizes, int n_in,
                              void* d_out, int out_size, void* d_ws, size_t ws_size,
                              hipStream_t stream) {
    const float* arr    = (const float*)d_in[0];  // [4,16,16,16,16,32]
    const float* Mmat   = (const float*)d_in[1];  // [32,32]
    const float* Acoeff = (const float*)d_in[2];  // [32,81]
    const float* Bbasis = (const float*)d_in[3];  // [81,32]
    float* dummy = (float*)d_ws;                  // scratch dest for replicas

    hipMemsetAsync(d_out, 0, 4 * 32 * sizeof(float), stream);
    // Real computation (identical to R3's passing kernel):
    sdd4_fused<<<dim3(1024), dim3(128), 0, stream>>>(arr, Mmat, Bbasis, Acoeff,
                                                     (float*)d_out);
    // Timing replicas: identical work, dummy destination in ws.
    // dur - dur_R3 = 3 x T_kernel  (replicas 2-4 run arr L3-warm).
    sdd4_fused<<<dim3(1024), dim3(128), 0, stream>>>(arr, Mmat, Bbasis, Acoeff, dummy);
    sdd4_fused<<<dim3(1024), dim3(128), 0, stream>>>(arr, Mmat, Bbasis, Acoeff, dummy);
    sdd4_fused<<<dim3(1024), dim3(128), 0, stream>>>(arr, Mmat, Bbasis, Acoeff, dummy);
}

// Round 5
// 87.709 us; speedup vs baseline: 1.4721x; 1.4721x over previous
//
#include <hip/hip_runtime.h>

// out[b,n] = 1/(16*50625) * sum_j Acoeff[n,j] * S[b,j]
// S[b,j]   = BM[j] . T[b,j],   BM = Bbasis @ M   (exact: R1 precedent)
// T[b,j,m] = sum_{p,q,r,s} w[j1][p] w[j2][q] w[j3][r] w[j4][s] * arr[b,p,q,r,s,m]
// w masks (per dim, D=16, L=3, window R=2, stride 1, VALID):
//   class0: 0x36DB  class1: 0x6DB6  class2: 0xDB6C
//
// R4 measurement: main kernel = 13.6us (L3-warm), tail-bound: the Y=M.V phase
// alone is ~3.7us/CU of scalar LDS reads, + a 36-long dependent global-load
// chain in the Acoeff fold. This version: BM hoisted to a parallel pre-kernel
// (kills Y), Acoeff staged to LDS (kills the load chain), fixed-36 combo lanes
// (wave1 skips), out zeroed by the pre-kernel (kills the memset dispatch).

static __device__ __forceinline__ void add4(float4& a, const float4& b) {
    a.x += b.x; a.y += b.y; a.z += b.z; a.w += b.w;
}
static __device__ __forceinline__ void fma4(float4& a, float w, const float4& b) {
    a.x = fmaf(w, b.x, a.x); a.y = fmaf(w, b.y, a.y);
    a.z = fmaf(w, b.z, a.z); a.w = fmaf(w, b.w, a.w);
}

// ---- pre-kernel: BM[j][m] = sum_n Bbasis[j][n] * M[n][m]; block0 zeroes out ----
__global__ __launch_bounds__(64) void sdd4_bm(
    const float* __restrict__ Mmat,     // [32,32]
    const float* __restrict__ Bbasis,   // [81,32]
    float* __restrict__ BM,             // [81,32] (ws)
    float* __restrict__ out)            // [4,32] zeroed here (stream-ordered)
{
    __shared__ float Bb_sh[32];
    const int t = threadIdx.x;
    const int j = blockIdx.x;            // 0..80
    if (j == 0) { out[t] = 0.f; out[64 + t] = 0.f; }
    if (t < 32) Bb_sh[t] = Bbasis[j * 32 + t];
    __syncthreads();
    if (t < 32) {
        float acc = 0.f;
        #pragma unroll                    // 32 independent coalesced M loads
        for (int n = 0; n < 32; ++n)
            acc = fmaf(Bb_sh[n], Mmat[n * 32 + t], acc);
        BM[j * 32 + t] = acc;
    }
}

__global__ __launch_bounds__(128) void sdd4_fused(
    const float* __restrict__ arr,      // [4,16,16,16,16,32]
    const float* __restrict__ BM,       // [81,32] precomputed Bbasis@M
    const float* __restrict__ Acoeff,   // [32,81]
    float* __restrict__ out)            // [4,32], zeroed by sdd4_bm
{
    __shared__ float4 U_lds[400];        // [r*25 + cls*8 + mv]  (pad 24->25)
    __shared__ float  V_lds[9 * 33];     // [jj*33 + m]
    __shared__ float  BM_lds[81 * 33];   // [jf*33 + m]
    __shared__ float4 A_lds4[648];       // Acoeff flat [n*81 + j] (stride 81: odd -> conflict-free)
    __shared__ float  pv[36];            // per-combo dot results
    __shared__ int    jfv[36];           // per-combo flat j index

    const int t  = threadIdx.x;
    const int bx = blockIdx.x;           // 0..1023
    const int b  = bx >> 8;
    const int p  = (bx >> 4) & 15;
    const int q  = bx & 15;

    // ---- stage BM (padded 33) and Acoeff (flat) into LDS ----
    const float4* BM4 = reinterpret_cast<const float4*>(BM);
    for (int i = t; i < 648; i += 128) {
        float4 v = BM4[i];
        float* dst = &BM_lds[(i >> 3) * 33 + (i & 7) * 4];
        dst[0] = v.x; dst[1] = v.y; dst[2] = v.z; dst[3] = v.w;
    }
    const float4* A4 = reinterpret_cast<const float4*>(Acoeff);
    for (int i = t; i < 648; i += 128) A_lds4[i] = A4[i];
    const float* A_lds = reinterpret_cast<const float*>(A_lds4);

    // ---- main global read: tile arr[b,p,q,:,:,:], reduce over s per class ----
    const int r  = t >> 3;               // 0..15
    const int mv = t & 7;                // float4 index within m
    const float4* Ar4 = reinterpret_cast<const float4*>(arr);
    const size_t tile = (size_t)((b * 16 + p) * 16 + q) * 2048;

    float4 u0 = make_float4(0.f, 0.f, 0.f, 0.f), u1 = u0, u2 = u0;
    #pragma unroll
    for (int s = 0; s < 16; ++s) {
        float4 x = Ar4[tile + (size_t)(r * 16 + s) * 8 + mv];
        if ((0x36DBu >> s) & 1) add4(u0, x);
        if ((0x6DB6u >> s) & 1) add4(u1, x);
        if ((0xDB6Cu >> s) & 1) add4(u2, x);
    }
    U_lds[r * 25 +      mv] = u0;
    U_lds[r * 25 +  8 + mv] = u1;
    U_lds[r * 25 + 16 + mv] = u2;
    __syncthreads();

    // ---- reduce over r per class: V[j3][j4][m] ----
    if (t < 72) {
        const int j3  = t / 24;
        const int rem = t % 24;
        const int j4  = rem >> 3;
        const int mv2 = rem & 7;
        const unsigned msk = (j3 == 0) ? 0x36DBu : (j3 == 1 ? 0x6DB6u : 0xDB6Cu);
        float4 acc = make_float4(0.f, 0.f, 0.f, 0.f);
        #pragma unroll
        for (int rr = 0; rr < 16; ++rr) {
            float w = (float)((msk >> rr) & 1u);
            fma4(acc, w, U_lds[rr * 25 + j4 * 8 + mv2]);
        }
        const int jj = j3 * 3 + j4;
        float* dv = &V_lds[jj * 33 + mv2 * 4];
        dv[0] = acc.x; dv[1] = acc.y; dv[2] = acc.z; dv[3] = acc.w;
    }
    __syncthreads();

    // ---- fixed 36 combo lanes: pv = BM[jf] . V[jj] (weight 0 if invalid) ----
    int l1_0, l1_1 = 0, n1;
    if      (p == 0)  { l1_0 = 0; n1 = 1; }
    else if (p == 15) { l1_0 = 2; n1 = 1; }
    else              { l1_0 = (p - 1) % 3; l1_1 = p % 3; n1 = 2; }
    int l2_0, l2_1 = 0, n2;
    if      (q == 0)  { l2_0 = 0; n2 = 1; }
    else if (q == 15) { l2_0 = 2; n2 = 1; }
    else              { l2_0 = (q - 1) % 3; l2_1 = q % 3; n2 = 2; }

    if (t < 36) {                        // wave1 never issues this loop
        const int jj   = t % 9;          // j3*3 + j4
        const int c12  = t / 9;          // 0..3
        const int asel = c12 >> 1;
        const int bsel = c12 & 1;
        const int i1 = asel ? l1_1 : l1_0;
        const int i2 = bsel ? l2_1 : l2_0;
        const bool ok = (!asel || n1 == 2) && (!bsel || n2 == 2);
        const int jf = (i1 * 3 + i2) * 9 + jj;
        float acc = 0.f;
        if (ok) {
            #pragma unroll
            for (int m = 0; m < 32; ++m)
                acc = fmaf(V_lds[jj * 33 + m], BM_lds[jf * 33 + m], acc);
        }
        pv[t]  = acc;                    // 0 for invalid/duplicate combos
        jfv[t] = jf;
    }
    __syncthreads();

    // ---- fold through Acoeff (LDS, unrolled), one atomic vector per block ----
    if (t < 32) {
        float acc = 0.f;
        #pragma unroll                   // compile-time bound -> pipelined LDS reads
        for (int c = 0; c < 36; ++c)
            acc = fmaf(A_lds[t * 81 + jfv[c]], pv[c], acc);
        atomicAdd(&out[b * 32 + t], acc * (1.0f / 810000.0f)); // 1/(16*15^4)
    }
}

extern "C" void kernel_launch(void* const* d_in, const int* in_sizes, int n_in,
                              void* d_out, int out_size, void* d_ws, size_t ws_size,
                              hipStream_t stream) {
    const float* arr    = (const float*)d_in[0];  // [4,16,16,16,16,32]
    const float* Mmat   = (const float*)d_in[1];  // [32,32]
    const float* Acoeff = (const float*)d_in[2];  // [32,81]
    const float* Bbasis = (const float*)d_in[3];  // [81,32]
    float* BM = (float*)d_ws;                     // 2592 floats

    sdd4_bm   <<<dim3(81),   dim3(64),  0, stream>>>(Mmat, Bbasis, BM, (float*)d_out);
    sdd4_fused<<<dim3(1024), dim3(128), 0, stream>>>(arr, BM, Acoeff, (float*)d_out);
}

// Round 6
// 83.859 us; speedup vs baseline: 1.5397x; 1.0459x over previous
//
#include <hip/hip_runtime.h>

// out[b,n] = 1/(16*50625) * sum_j Acoeff[n,j] * S[b,j]
// S[b,j]   = sum_n Bbasis[j,n] * (M @ T[b,j])[n]
// T[b,j,m] = sum_{p,q,r,s} w[j1][p] w[j2][q] w[j3][r] w[j4][s] * arr[b,p,q,r,s,m]
// w masks (per dim, D=16, L=3, window R=2, stride 1, VALID):
//   class0: 0x36DB  class1: 0x6DB6  class2: 0xDB6C
//
// R4 replica measurement: fused kernel = 13.6us warm vs 5.5us HBM floor; the
// gap is the per-block tail (21KB BM/Acoeff staging, combo dots, Acoeff fold,
// atomic funnel) serialized behind the load. This version splits:
//   K1 (1024 blks): pure stream -> s-reduce -> r-reduce -> direct global store
//       of V[b][jj][p][q][m] (1.18MB ws). 1 barrier, 6.4KB LDS, no atomics.
//   K2 (36 blks = (b,jj)): contiguous 32KB V slab -> 9 mask-weighted (i1,i2)
//       sums over (p,q) (same class masks applied to p,q) -> M matvecs ->
//       Bbasis dots -> Acoeff fold -> one 32-lane atomicAdd per block.

static __device__ __forceinline__ void add4(float4& a, const float4& b) {
    a.x += b.x; a.y += b.y; a.z += b.z; a.w += b.w;
}
static __device__ __forceinline__ void fma4(float4& a, float w, const float4& b) {
    a.x = fmaf(w, b.x, a.x); a.y = fmaf(w, b.y, a.y);
    a.z = fmaf(w, b.z, a.z); a.w = fmaf(w, b.w, a.w);
}

__global__ __launch_bounds__(128) void sdd4_v(
    const float* __restrict__ arr,      // [4,16,16,16,16,32]
    float* __restrict__ V,              // [4][9][16][16][32] ws
    float* __restrict__ out)            // [4,32] zeroed here (block 0)
{
    __shared__ float4 U_lds[400];        // [r*25 + cls*8 + mv]  (pad 24->25)

    const int t  = threadIdx.x;
    const int bx = blockIdx.x;           // 0..1023
    const int b  = bx >> 8;
    const int p  = (bx >> 4) & 15;
    const int q  = bx & 15;

    if (bx == 0) out[t] = 0.f;           // 128 floats, stream-ordered before K2

    const int r  = t >> 3;               // 0..15
    const int mv = t & 7;                // float4 index within m
    const float4* A4 = reinterpret_cast<const float4*>(arr);
    const size_t tile = (size_t)((b * 16 + p) * 16 + q) * 2048;

    float4 u0 = make_float4(0.f, 0.f, 0.f, 0.f), u1 = u0, u2 = u0;
    #pragma unroll
    for (int s = 0; s < 16; ++s) {
        float4 x = A4[tile + (size_t)(r * 16 + s) * 8 + mv];
        if ((0x36DBu >> s) & 1) add4(u0, x);
        if ((0x6DB6u >> s) & 1) add4(u1, x);
        if ((0xDB6Cu >> s) & 1) add4(u2, x);
    }
    U_lds[r * 25 +      mv] = u0;
    U_lds[r * 25 +  8 + mv] = u1;
    U_lds[r * 25 + 16 + mv] = u2;
    __syncthreads();

    // r-reduce per class; each active lane stores its float4 straight to V
    if (t < 72) {
        const int j3  = t / 24;
        const int rem = t % 24;
        const int j4  = rem >> 3;
        const int mv2 = rem & 7;
        const unsigned msk = (j3 == 0) ? 0x36DBu : (j3 == 1 ? 0x6DB6u : 0xDB6Cu);
        float4 acc = make_float4(0.f, 0.f, 0.f, 0.f);
        #pragma unroll
        for (int rr = 0; rr < 16; ++rr) {
            float w = (float)((msk >> rr) & 1u);
            fma4(acc, w, U_lds[rr * 25 + j4 * 8 + mv2]);
        }
        const int jj = j3 * 3 + j4;
        float4* V4 = reinterpret_cast<float4*>(V);
        V4[((b * 9 + jj) * 256 + p * 16 + q) * 8 + mv2] = acc;
    }
}

__global__ __launch_bounds__(256) void sdd4_reduce(
    const float* __restrict__ V,        // [4][9][256][32] ws
    const float* __restrict__ Mmat,     // [32,32]
    const float* __restrict__ Bbasis,   // [81,32]
    const float* __restrict__ Acoeff,   // [32,81]
    float* __restrict__ out)            // [4,32] pre-zeroed by K1
{
    __shared__ float M_lds[32 * 33];
    __shared__ float Bb_lds[9 * 33];
    __shared__ float Vp[8 * 9 * 33];     // per-group partial [g][c][m]
    __shared__ float Vs[9 * 33];         // [c][m]
    __shared__ float Y_lds[9 * 33];      // [c][n]
    __shared__ float Sf[9];

    const int t   = threadIdx.x;         // 0..255
    const int blk = blockIdx.x;          // 0..35
    const int b   = blk / 9;
    const int jj  = blk % 9;

    // stage M (padded) and the 9 Bbasis rows jf = c*9 + jj
    const float4* M4 = reinterpret_cast<const float4*>(Mmat);
    if (t < 256) {
        float4 v = M4[t];
        float* dst = &M_lds[(t >> 3) * 33 + (t & 7) * 4];
        dst[0] = v.x; dst[1] = v.y; dst[2] = v.z; dst[3] = v.w;
    }
    const float4* B4 = reinterpret_cast<const float4*>(Bbasis);
    if (t < 72) {
        const int k = t >> 3, f4 = t & 7;
        float4 v = B4[(k * 9 + jj) * 8 + f4];
        float* dst = &Bb_lds[k * 33 + f4 * 4];
        dst[0] = v.x; dst[1] = v.y; dst[2] = v.z; dst[3] = v.w;
    }

    // masked (p,q) accumulation: 8 groups x 32 pq each, lane owns m
    const int g = t >> 5;                // 0..7
    const int m = t & 31;
    const float* Vb = V + (size_t)blk * 8192;   // [256][32] slab
    float acc[9];
    #pragma unroll
    for (int c = 0; c < 9; ++c) acc[c] = 0.f;
    #pragma unroll 4
    for (int u = 0; u < 32; ++u) {
        const int pq = g * 32 + u;
        const int p  = pq >> 4;
        const int q  = pq & 15;
        const float v = Vb[pq * 32 + m];
        const unsigned e1 = ((0x36DBu >> p) & 1u) | (((0x6DB6u >> p) & 1u) << 1)
                          | (((0xDB6Cu >> p) & 1u) << 2);
        const unsigned e2 = ((0x36DBu >> q) & 1u) | (((0x6DB6u >> q) & 1u) << 1)
                          | (((0xDB6Cu >> q) & 1u) << 2);
        #pragma unroll
        for (int c = 0; c < 9; ++c)
            if (((e1 >> (c / 3)) & 1u) && ((e2 >> (c % 3)) & 1u))
                acc[c] += v;
    }
    #pragma unroll
    for (int c = 0; c < 9; ++c) Vp[(g * 9 + c) * 33 + m] = acc[c];
    __syncthreads();

    // Vs[c][m] = sum_g Vp[g][c][m]
    for (int o = t; o < 288; o += 256) {
        const int c = o >> 5, mm = o & 31;
        float s = 0.f;
        #pragma unroll
        for (int gg = 0; gg < 8; ++gg) s += Vp[(gg * 9 + c) * 33 + mm];
        Vs[c * 33 + mm] = s;
    }
    __syncthreads();

    // Y[c][n] = sum_m M[n][m] * Vs[c][m]
    for (int o = t; o < 288; o += 256) {
        const int c = o >> 5, n = o & 31;
        float s = 0.f;
        #pragma unroll
        for (int mm = 0; mm < 32; ++mm)
            s = fmaf(M_lds[n * 33 + mm], Vs[c * 33 + mm], s);
        Y_lds[c * 33 + n] = s;
    }
    __syncthreads();

    // Sf[c] = Bbasis[c*9+jj] . Y[c]
    if (t < 9) {
        float s = 0.f;
        #pragma unroll
        for (int n = 0; n < 32; ++n)
            s = fmaf(Bb_lds[t * 33 + n], Y_lds[t * 33 + n], s);
        Sf[t] = s;
    }
    __syncthreads();

    // fold Acoeff for this jj; one 32-lane atomic vector per block (36 total)
    if (t < 32) {
        float z = 0.f;
        #pragma unroll
        for (int c = 0; c < 9; ++c)
            z = fmaf(Acoeff[t * 81 + c * 9 + jj], Sf[c], z);
        atomicAdd(&out[b * 32 + t], z * (1.0f / 810000.0f));  // 1/(16*15^4)
    }
}

extern "C" void kernel_launch(void* const* d_in, const int* in_sizes, int n_in,
                              void* d_out, int out_size, void* d_ws, size_t ws_size,
                              hipStream_t stream) {
    const float* arr    = (const float*)d_in[0];  // [4,16,16,16,16,32]
    const float* Mmat   = (const float*)d_in[1];  // [32,32]
    const float* Acoeff = (const float*)d_in[2];  // [32,81]
    const float* Bbasis = (const float*)d_in[3];  // [81,32]
    float* V = (float*)d_ws;                      // 4*9*256*32 floats = 1.18 MB

    sdd4_v     <<<dim3(1024), dim3(128), 0, stream>>>(arr, V, (float*)d_out);
    sdd4_reduce<<<dim3(36),   dim3(256), 0, stream>>>(V, Mmat, Bbasis, Acoeff,
                                                      (float*)d_out);
}